// Round 5
// baseline (364.164 us; speedup 1.0000x reference)
//
#include <hip/hip_runtime.h>
#include <hip/hip_bf16.h>
#include <stdint.h>

#define B_ 8
#define S_ 4096
#define D_ 512
#define G_ 64
#define R_ 1024
#define NO_ 4096
#define SO_ 3072   /* S_ - R_ */
#define EPS_MERGE 1e-8f
#define EPS_NORM 1e-12f

typedef float f4v __attribute__((ext_vector_type(4)));

// workspace byte offsets
#define WS_GN    0ull            // gn: 32768 f32   = 131072 B
#define WS_KEYS  131072ull       // prio: 8*4096 u64 = 262144 B
#define WS_KEPT  393216ull       // kept: 8*3072 u32 = 98304 B

// ---------------- k12: fused projection + sim ---------------------------
// 256 blocks x 256 threads; block owns rows rb..rb+127 and edges
// rb..rb+127 (126 for batch-last block). Boundary row rb+128's g/gn are
// recomputed with the EXACT FMA/reduce order of the next block's row 0,
// so sims are bitwise identical to the unfused version. g never touches
// global memory.
__global__ __launch_bounds__(256) void k12_proj_sim(const float* __restrict__ x,
                                                    const float* __restrict__ W,
                                                    float* __restrict__ gn,
                                                    unsigned long long* __restrict__ prio) {
  __shared__ union {
    struct { float xs[32][132]; float wc[32][68]; } s;  // GEMM staging
    float gs[129][66];                                  // g rows + norms (col 64)
  } u;
  const int tid = threadIdx.x;
  const int gt  = tid & 15;
  const int rt  = tid >> 4;
  const int rb  = blockIdx.x * 128;
  const int g0  = gt * 4;
  const int r0  = rt * 8;
  const int kq4 = (tid & 7) * 4;   // staged k sub-offset
  const int rl0 = tid >> 3;        // staged row/g (+ i*32)

  const float* xp[4];
  const float* wp[2];
#pragma unroll
  for (int i = 0; i < 4; ++i)
    xp[i] = &x[(size_t)(rb + rl0 + i * 32) * D_ + kq4];
#pragma unroll
  for (int i = 0; i < 2; ++i)
    wp[i] = &W[(size_t)(rl0 + i * 32) * D_ + kq4];
  // boundary row (clamped only for the final block; unused there)
  const int rowB = (rb + 128 < B_ * S_) ? rb + 128 : B_ * S_ - 1;
  const float* xbp = &x[(size_t)rowB * D_ + tid * 4];  // deref only tid<8

  float4 px[4], pw[2], pxb;
#pragma unroll
  for (int i = 0; i < 4; ++i) px[i] = *reinterpret_cast<const float4*>(xp[i]);
#pragma unroll
  for (int i = 0; i < 2; ++i) pw[i] = *reinterpret_cast<const float4*>(wp[i]);
  if (tid < 8) pxb = *reinterpret_cast<const float4*>(xbp);

  float acc[8][4];
#pragma unroll
  for (int r = 0; r < 8; ++r)
#pragma unroll
    for (int j = 0; j < 4; ++j) acc[r][j] = 0.f;
  float accB[4] = {0.f, 0.f, 0.f, 0.f};   // boundary row, tid<16 (g0b=tid*4)

  for (int kc = 0; kc < 16; ++kc) {
    __syncthreads();   // previous chunk fully consumed
#pragma unroll
    for (int i = 0; i < 4; ++i) {
      const int rl = rl0 + i * 32;
      u.s.xs[kq4 + 0][rl] = px[i].x;
      u.s.xs[kq4 + 1][rl] = px[i].y;
      u.s.xs[kq4 + 2][rl] = px[i].z;
      u.s.xs[kq4 + 3][rl] = px[i].w;
    }
#pragma unroll
    for (int i = 0; i < 2; ++i) {
      const int gg = rl0 + i * 32;
      u.s.wc[kq4 + 0][gg] = pw[i].x;
      u.s.wc[kq4 + 1][gg] = pw[i].y;
      u.s.wc[kq4 + 2][gg] = pw[i].z;
      u.s.wc[kq4 + 3][gg] = pw[i].w;
    }
    if (tid < 8) {   // boundary row staged at column 128
      u.s.xs[tid * 4 + 0][128] = pxb.x;
      u.s.xs[tid * 4 + 1][128] = pxb.y;
      u.s.xs[tid * 4 + 2][128] = pxb.z;
      u.s.xs[tid * 4 + 3][128] = pxb.w;
    }
    if (kc < 15) {
      const int off = (kc + 1) * 32;
#pragma unroll
      for (int i = 0; i < 4; ++i)
        px[i] = *reinterpret_cast<const float4*>(xp[i] + off);
#pragma unroll
      for (int i = 0; i < 2; ++i)
        pw[i] = *reinterpret_cast<const float4*>(wp[i] + off);
      if (tid < 8) pxb = *reinterpret_cast<const float4*>(xbp + off);
    }
    __syncthreads();   // chunk kc visible in LDS
#pragma unroll
    for (int k = 0; k < 32; ++k) {
      const float4 wv = *reinterpret_cast<const float4*>(&u.s.wc[k][g0]);
      const float4 xa = *reinterpret_cast<const float4*>(&u.s.xs[k][r0]);
      const float4 xb = *reinterpret_cast<const float4*>(&u.s.xs[k][r0 + 4]);
      const float xr[8] = {xa.x, xa.y, xa.z, xa.w, xb.x, xb.y, xb.z, xb.w};
#pragma unroll
      for (int r = 0; r < 8; ++r) {
        acc[r][0] = fmaf(xr[r], wv.x, acc[r][0]);
        acc[r][1] = fmaf(xr[r], wv.y, acc[r][1]);
        acc[r][2] = fmaf(xr[r], wv.z, acc[r][2]);
        acc[r][3] = fmaf(xr[r], wv.w, acc[r][3]);
      }
    }
    if (tid < 16) {   // boundary row: same (kc,k,j) FMA order as main path
#pragma unroll
      for (int k = 0; k < 32; ++k) {
        const float xb1 = u.s.xs[k][128];
        const float4 wv = *reinterpret_cast<const float4*>(&u.s.wc[k][tid * 4]);
        accB[0] = fmaf(xb1, wv.x, accB[0]);
        accB[1] = fmaf(xb1, wv.y, accB[1]);
        accB[2] = fmaf(xb1, wv.z, accB[2]);
        accB[3] = fmaf(xb1, wv.w, accB[3]);
      }
    }
  }

  __syncthreads();   // all xs/wc reads done -> safe to repurpose union as gs

  // write g rows to LDS + norms (identical reduce tree to unfused k1)
#pragma unroll
  for (int r = 0; r < 8; ++r) {
    const int rl = r0 + r;
    float4 v;
    v.x = acc[r][0]; v.y = acc[r][1]; v.z = acc[r][2]; v.w = acc[r][3];
    *reinterpret_cast<float4*>(&u.gs[rl][g0]) = v;
    float ss = v.x * v.x + v.y * v.y + v.z * v.z + v.w * v.w;
    ss += __shfl_xor(ss, 1);
    ss += __shfl_xor(ss, 2);
    ss += __shfl_xor(ss, 4);
    ss += __shfl_xor(ss, 8);
    if (gt == 0) {
      const float nv = sqrtf(ss);
      gn[rb + rl] = nv;
      u.gs[rl][64] = nv;
    }
  }
  if (tid < 16) {   // boundary row: lanes 0..15 == gt, same xor tree
    *reinterpret_cast<float4*>(&u.gs[128][tid * 4]) =
        make_float4(accB[0], accB[1], accB[2], accB[3]);
    float ss = accB[0] * accB[0] + accB[1] * accB[1] +
               accB[2] * accB[2] + accB[3] * accB[3];
    ss += __shfl_xor(ss, 1);
    ss += __shfl_xor(ss, 2);
    ss += __shfl_xor(ss, 4);
    ss += __shfl_xor(ss, 8);
    if (tid == 0) u.gs[128][64] = sqrtf(ss);   // NOT written to global
  }
  __syncthreads();

  // sim phase: wave w handles edges rb + w*32 + i (identical reduce to k2)
  const int lastLe = ((rb & (S_ - 1)) == S_ - 128) ? 126 : 127;
  const int wv_ = tid >> 6, lane = tid & 63;
  const int bb = rb >> 12;
  const int e0 = rb & (S_ - 1);
#pragma unroll 2
  for (int i = 0; i < 32; ++i) {
    const int le = wv_ * 32 + i;
    if (le > lastLe) break;
    const float a = u.gs[le][lane];
    const float c = u.gs[le + 1][lane];
    float p = a * c;
    p += __shfl_xor(p, 1);
    p += __shfl_xor(p, 2);
    p += __shfl_xor(p, 4);
    p += __shfl_xor(p, 8);
    p += __shfl_xor(p, 16);
    p += __shfl_xor(p, 32);
    if (lane == 0) {
      const float n0 = fmaxf(u.gs[le][64], EPS_NORM);
      const float n1 = fmaxf(u.gs[le + 1][64], EPS_NORM);
      const float sim = p / (n0 * n1);
      const unsigned int uu = __float_as_uint(sim);
      const unsigned int mm = (uu & 0x80000000u) ? ~uu : (uu | 0x80000000u);
      const int e = e0 + le;
      prio[(size_t)bb * S_ + e] =
          ((unsigned long long)mm << 32) | (unsigned long long)(unsigned int)(4095 - e);
    }
  }
}

// ---------------- k3: bit-parallel greedy matching + radix top-R ----------
__global__ __launch_bounds__(256) void k3_match(const unsigned long long* __restrict__ prio,
                                                unsigned int* __restrict__ kept) {
  __shared__ unsigned long long pr[4096];     // 32 KB
  __shared__ unsigned int stw[258];
  __shared__ int hist[256];
  __shared__ int wsum[4];
  __shared__ int sh_flag;
  __shared__ int sh_need;
  __shared__ int sh_exact;
  __shared__ unsigned long long sh_prefix;
  __shared__ unsigned long long sh_tmin;
  __shared__ unsigned long long sh_tmax;

  const int tid = threadIdx.x;
  const int b = blockIdx.x;

#pragma unroll
  for (int j = 0; j < 16; ++j) {
    const int e = tid + j * 256;
    pr[e] = (e < 4095) ? prio[(size_t)b * S_ + e] : 0ull;
  }
  if (tid == 0) {
    stw[0] = 0xAAAAAAAAu;
    stw[257] = 0xAAAAAAAAu;
    sh_flag = 0; sh_need = R_; sh_prefix = 0ull;
    sh_exact = 0; sh_tmin = ~0ull; sh_tmax = 0ull;
  }
  stw[1 + tid] = (tid == 255) ? 0x80000000u : 0u;
  __syncthreads();

  unsigned int cl = 0, cr = 0;
#pragma unroll
  for (int j = 0; j < 16; ++j) {
    const int e = tid * 16 + j;
    const unsigned long long pe = pr[e];
    const bool L = (e == 0) || (pe > pr[e - 1]);
    const bool R = (e >= 4094) || (pe > pr[e + 1]);
    cl |= (L ? 1u : 0u) << (2 * j);
    cr |= (R ? 1u : 0u) << (2 * j);
  }

  for (;;) {
    __syncthreads();
    if (tid == 0) sh_flag = 0;
    __syncthreads();
    unsigned int u = stw[1 + tid];
    const unsigned int lw = stw[tid];
    const unsigned int rw = stw[2 + tid];
    const unsigned int linb = (lw >> 30) & 1u;
    const unsigned int loutb = (lw >> 31) & 1u;
    const unsigned int rinb = (rw & 1u) << 30;
    const unsigned int routb = ((rw >> 1) & 1u) << 30;
    bool changed = false;
    for (;;) {
      const unsigned int a = u & 0x55555555u;
      const unsigned int d = (u >> 1) & 0x55555555u;
      const unsigned int lin = (a << 2) | linb;
      const unsigned int lout = (d << 2) | loutb;
      const unsigned int rin = (a >> 2) | rinb;
      const unsigned int rout = (d >> 2) | routb;
      const unsigned int undec = ~(a | d) & 0x55555555u;
      const unsigned int nout = undec & (lin | rin);
      const unsigned int nin = undec & ~lin & ~rin & (lout | cl) & (rout | cr);
      if (!(nin | nout)) break;
      u |= nin | (nout << 1);
      changed = true;
    }
    if (changed) { stw[1 + tid] = u; sh_flag = 1; }
    __syncthreads();
    if (sh_flag == 0) break;
  }

  const unsigned int inw = stw[1 + tid] & 0x55555555u;

  int exitmode = 0;
#pragma unroll 1
  for (int level = 0; level < 8; ++level) {
    const int shift = 56 - 8 * level;
    __syncthreads();
    hist[tid] = 0;
    __syncthreads();
    const unsigned long long pref = sh_prefix;
#pragma unroll
    for (int j = 0; j < 16; ++j) {
      if (!((inw >> (2 * j)) & 1u)) continue;
      const unsigned long long p = pr[tid * 16 + j];
      const bool match = (level == 0) || ((p >> (shift + 8)) == (pref >> (shift + 8)));
      if (match) atomicAdd(&hist[(int)((p >> shift) & 255ull)], 1);
    }
    __syncthreads();
    if (tid < 64) {
      const int lane = tid;
      const int need = sh_need;
      const int h0 = hist[lane * 4 + 0], h1 = hist[lane * 4 + 1];
      const int h2 = hist[lane * 4 + 2], h3 = hist[lane * 4 + 3];
      const int gsum = h0 + h1 + h2 + h3;
      int s = gsum;
#pragma unroll
      for (int off = 1; off < 64; off <<= 1) {
        const int v = __shfl_down(s, off);
        if (lane + off < 64) s += v;
      }
      const int suffAbove = s - gsum;
      if (suffAbove < need && s >= need) {
        const int hh[4] = {h0, h1, h2, h3};
        int cum = suffAbove;
        for (int q = 3; q >= 0; --q) {
          cum += hh[q];
          if (cum >= need) {
            const int need2 = need - (cum - hh[q]);
            sh_prefix = pref | ((unsigned long long)(lane * 4 + q) << shift);
            sh_need = need2;
            if (need2 == hh[q]) sh_exact = 1;
            else if (need2 == 1) sh_exact = 2;
            break;
          }
        }
      }
    }
    __syncthreads();
    const int ex = sh_exact;
    if (ex) {
      exitmode = ex;
      const unsigned long long pref2 = sh_prefix;
      unsigned long long best = (ex == 1) ? ~0ull : 0ull;
#pragma unroll
      for (int j = 0; j < 16; ++j) {
        if (!((inw >> (2 * j)) & 1u)) continue;
        const unsigned long long p = pr[tid * 16 + j];
        if ((p >> shift) == (pref2 >> shift))
          best = (ex == 1) ? (best < p ? best : p) : (best > p ? best : p);
      }
#pragma unroll
      for (int off = 1; off < 64; off <<= 1) {
        const unsigned long long o = __shfl_xor(best, off);
        best = (ex == 1) ? (best < o ? best : o) : (best > o ? best : o);
      }
      if ((tid & 63) == 0) {
        if (ex == 1) atomicMin(&sh_tmin, best);
        else atomicMax(&sh_tmax, best);
      }
      __syncthreads();
      break;
    }
  }
  const unsigned long long thresh =
      (exitmode == 1) ? sh_tmin : (exitmode == 2) ? sh_tmax : sh_prefix;
  const unsigned int previnw = stw[tid] & 0x55555555u;

  int c = 0;
  unsigned int kpbits = 0;
#pragma unroll
  for (int j = 0; j < 16; ++j) {
    const int s = tid * 16 + j;
    bool selprev = false;
    if (s > 0) {
      const unsigned int ib =
          (j == 0) ? ((previnw >> 30) & 1u) : ((inw >> (2 * (j - 1))) & 1u);
      selprev = ib && (pr[s - 1] >= thresh);
    }
    if (!selprev) { kpbits |= 1u << j; ++c; }
  }
  const int lane = tid & 63, w = tid >> 6;
  int v = c;
#pragma unroll
  for (int off = 1; off < 64; off <<= 1) {
    const int t2 = __shfl_up(v, off);
    if (lane >= off) v += t2;
  }
  if (lane == 63) wsum[w] = v;
  __syncthreads();
  if (tid == 0) {
    int run = 0;
    for (int q = 0; q < 4; ++q) { const int t3 = wsum[q]; wsum[q] = run; run += t3; }
  }
  __syncthreads();
  int pos = (v - c) + wsum[w];
#pragma unroll
  for (int j = 0; j < 16; ++j) {
    if ((kpbits >> j) & 1u) {
      const int s = tid * 16 + j;
      const unsigned int m =
          (((inw >> (2 * j)) & 1u) && pr[s] >= thresh) ? 0x80000000u : 0u;
      kept[b * SO_ + pos] = (unsigned int)s | m;
      ++pos;
    }
  }
}

// ---------------- k45: fused src + x + pos gather/merge -------------------
__global__ __launch_bounds__(256) void k45_gather(const float* __restrict__ src,
                                                  const float* __restrict__ x,
                                                  const float* __restrict__ gn,
                                                  const int* __restrict__ posid,
                                                  const unsigned int* __restrict__ kept,
                                                  float* __restrict__ outs,
                                                  float* __restrict__ outx,
                                                  float* __restrict__ outpos) {
  const int blk = blockIdx.x;
  const int b = blk / SO_;
  const int j = blk - b * SO_;
  const unsigned int ent = kept[b * SO_ + j];
  const int s = (int)(ent & 0x7FFFFFFFu);
  const bool m = (ent & 0x80000000u) != 0u;
  const size_t rrow = (size_t)b * S_ + s;
  const size_t orow = (size_t)b * SO_ + j;
  const size_t rin = rrow * NO_;
  const size_t rout = orow * NO_;
  const int t = threadIdx.x;

  // src row (16 KB), streaming: non-temporal
#pragma unroll
  for (int it = 0; it < 4; ++it) {
    const int f4 = t + it * 256;
    f4v a = __builtin_nontemporal_load(
        reinterpret_cast<const f4v*>(&src[rin + (size_t)f4 * 4]));
    if (m) {
      const f4v c2 = __builtin_nontemporal_load(
          reinterpret_cast<const f4v*>(&src[rin + NO_ + (size_t)f4 * 4]));
      a += c2;
    }
    __builtin_nontemporal_store(a, reinterpret_cast<f4v*>(&outs[rout + (size_t)f4 * 4]));
  }

  // x row (2 KB) on threads 0..127, also streaming
  if (t < 128) {
    f4v a = __builtin_nontemporal_load(
        reinterpret_cast<const f4v*>(&x[rrow * D_ + t * 4]));
    f4v o;
    if (m) {
      const float w0 = gn[rrow], w1 = gn[rrow + 1];
      const f4v c2 = __builtin_nontemporal_load(
          reinterpret_cast<const f4v*>(&x[(rrow + 1) * D_ + t * 4]));
      const float den = w0 + w1 + EPS_MERGE;
      o.x = (w0 * a.x + w1 * c2.x) / den;
      o.y = (w0 * a.y + w1 * c2.y) / den;
      o.z = (w0 * a.z + w1 * c2.z) / den;
      o.w = (w0 * a.w + w1 * c2.w) / den;
    } else {
      o = a;
    }
    __builtin_nontemporal_store(o, reinterpret_cast<f4v*>(&outx[orow * D_ + t * 4]));
  }
  if (t == 0) outpos[orow] = (float)posid[rrow];
}

extern "C" void kernel_launch(void* const* d_in, const int* in_sizes, int n_in,
                              void* d_out, int out_size, void* d_ws, size_t ws_size,
                              hipStream_t stream) {
  (void)in_sizes; (void)n_in; (void)out_size; (void)ws_size;
  const float* x = (const float*)d_in[0];
  const float* src = (const float*)d_in[1];
  const int* posid = (const int*)d_in[2];
  const float* W = (const float*)d_in[3];

  char* ws = (char*)d_ws;
  float* gn = (float*)(ws + WS_GN);
  unsigned long long* prio = (unsigned long long*)(ws + WS_KEYS);
  unsigned int* kept = (unsigned int*)(ws + WS_KEPT);

  float* outx = (float*)d_out;
  float* outs = outx + (size_t)B_ * SO_ * D_;
  float* outpos = outs + (size_t)B_ * SO_ * NO_;

  hipLaunchKernelGGL(k12_proj_sim, dim3(256), dim3(256), 0, stream, x, W, gn, prio);
  hipLaunchKernelGGL(k3_match, dim3(B_), dim3(256), 0, stream, prio, kept);
  hipLaunchKernelGGL(k45_gather, dim3(B_ * SO_), dim3(256), 0, stream, src, x, gn,
                     posid, kept, outs, outx, outpos);
}

// Round 6
// 237.286 us; speedup vs baseline: 1.5347x; 1.5347x over previous
//
#include <hip/hip_runtime.h>
#include <hip/hip_bf16.h>
#include <stdint.h>

#define B_ 8
#define S_ 4096
#define D_ 512
#define G_ 64
#define R_ 1024
#define NO_ 4096
#define SO_ 3072   /* S_ - R_ */
#define EPS_MERGE 1e-8f
#define EPS_NORM 1e-12f

typedef float f4v __attribute__((ext_vector_type(4)));

// workspace byte offsets
#define WS_G     0ull                 // g: 32768*64 f32   = 8388608 B
#define WS_GN    8388608ull           // gn: 32768 f32     = 131072 B
#define WS_KEYS  8519680ull           // prio: 8*4096 u64  = 262144 B
#define WS_KEPT  8781824ull           // kept: 8*3072 u32  = 98304 B

// ---------------- k1: g = x @ W^T  (M=32768, N=64, K=512) + row norms ----
// 256 blocks x 256 threads, 128 rows/block, thread = 8 rows x 4 g.
// Register double-buffer: prefetch chunk kc+1 into VGPRs during FMA of kc.
__global__ __launch_bounds__(256) void k1_proj(const float* __restrict__ x,
                                               const float* __restrict__ W,
                                               float* __restrict__ g,
                                               float* __restrict__ gn) {
  __shared__ float xs[32][132];
  __shared__ float wc[32][68];
  const int tid = threadIdx.x;
  const int gt  = tid & 15;
  const int rt  = tid >> 4;
  const int rb  = blockIdx.x * 128;
  const int g0  = gt * 4;
  const int r0  = rt * 8;
  const int kq4 = (tid & 7) * 4;   // k sub-offset this thread stages
  const int rl0 = tid >> 3;        // row/g staged (+ i*32)

  const float* xp[4];
  const float* wp[2];
#pragma unroll
  for (int i = 0; i < 4; ++i)
    xp[i] = &x[(size_t)(rb + rl0 + i * 32) * D_ + kq4];
#pragma unroll
  for (int i = 0; i < 2; ++i)
    wp[i] = &W[(size_t)(rl0 + i * 32) * D_ + kq4];

  float4 px[4], pw[2];
#pragma unroll
  for (int i = 0; i < 4; ++i) px[i] = *reinterpret_cast<const float4*>(xp[i]);
#pragma unroll
  for (int i = 0; i < 2; ++i) pw[i] = *reinterpret_cast<const float4*>(wp[i]);

  float acc[8][4];
#pragma unroll
  for (int r = 0; r < 8; ++r)
#pragma unroll
    for (int j = 0; j < 4; ++j) acc[r][j] = 0.f;

  for (int kc = 0; kc < 16; ++kc) {
    __syncthreads();   // previous chunk fully consumed
#pragma unroll
    for (int i = 0; i < 4; ++i) {
      const int rl = rl0 + i * 32;
      xs[kq4 + 0][rl] = px[i].x;
      xs[kq4 + 1][rl] = px[i].y;
      xs[kq4 + 2][rl] = px[i].z;
      xs[kq4 + 3][rl] = px[i].w;
    }
#pragma unroll
    for (int i = 0; i < 2; ++i) {
      const int gg = rl0 + i * 32;
      wc[kq4 + 0][gg] = pw[i].x;
      wc[kq4 + 1][gg] = pw[i].y;
      wc[kq4 + 2][gg] = pw[i].z;
      wc[kq4 + 3][gg] = pw[i].w;
    }
    if (kc < 15) {
      const int off = (kc + 1) * 32;
#pragma unroll
      for (int i = 0; i < 4; ++i)
        px[i] = *reinterpret_cast<const float4*>(xp[i] + off);
#pragma unroll
      for (int i = 0; i < 2; ++i)
        pw[i] = *reinterpret_cast<const float4*>(wp[i] + off);
    }
    __syncthreads();   // chunk kc visible in LDS
#pragma unroll
    for (int k = 0; k < 32; ++k) {
      const float4 wv = *reinterpret_cast<const float4*>(&wc[k][g0]);
      const float4 xa = *reinterpret_cast<const float4*>(&xs[k][r0]);
      const float4 xb = *reinterpret_cast<const float4*>(&xs[k][r0 + 4]);
      const float xr[8] = {xa.x, xa.y, xa.z, xa.w, xb.x, xb.y, xb.z, xb.w};
#pragma unroll
      for (int r = 0; r < 8; ++r) {
        acc[r][0] = fmaf(xr[r], wv.x, acc[r][0]);
        acc[r][1] = fmaf(xr[r], wv.y, acc[r][1]);
        acc[r][2] = fmaf(xr[r], wv.z, acc[r][2]);
        acc[r][3] = fmaf(xr[r], wv.w, acc[r][3]);
      }
    }
  }
#pragma unroll
  for (int r = 0; r < 8; ++r) {
    const int row = rb + r0 + r;
    float4 v;
    v.x = acc[r][0]; v.y = acc[r][1]; v.z = acc[r][2]; v.w = acc[r][3];
    *reinterpret_cast<float4*>(&g[(size_t)row * G_ + g0]) = v;
    float ss = v.x * v.x + v.y * v.y + v.z * v.z + v.w * v.w;
    ss += __shfl_xor(ss, 1);
    ss += __shfl_xor(ss, 2);
    ss += __shfl_xor(ss, 4);
    ss += __shfl_xor(ss, 8);
    if (gt == 0) gn[row] = sqrtf(ss);
  }
}

// ---------------- k2: sim -> priority key (one wave per edge) -------------
// prio[e] = mono(sim) << 32 | (4095 - e): higher = earlier in greedy order.
__global__ __launch_bounds__(256) void k2_sim(const float* __restrict__ g,
                                              const float* __restrict__ gn,
                                              unsigned long long* __restrict__ prio) {
  const int wid = blockIdx.x * 4 + (threadIdx.x >> 6);
  const int lane = threadIdx.x & 63;
  if (wid >= B_ * (S_ - 1)) return;
  const int b = wid / (S_ - 1);
  const int e = wid - b * (S_ - 1);
  const size_t row = (size_t)b * S_ + e;
  const float a = g[row * G_ + lane];
  const float c = g[(row + 1) * G_ + lane];
  float p = a * c;
  p += __shfl_xor(p, 1);
  p += __shfl_xor(p, 2);
  p += __shfl_xor(p, 4);
  p += __shfl_xor(p, 8);
  p += __shfl_xor(p, 16);
  p += __shfl_xor(p, 32);
  if (lane == 0) {
    const float n0 = fmaxf(gn[row], EPS_NORM);
    const float n1 = fmaxf(gn[row + 1], EPS_NORM);
    const float sim = p / (n0 * n1);
    const unsigned int u = __float_as_uint(sim);
    const unsigned int m = (u & 0x80000000u) ? ~u : (u | 0x80000000u);
    prio[(size_t)b * S_ + e] =
        ((unsigned long long)m << 32) | (unsigned long long)(unsigned int)(4095 - e);
  }
}

// ---------------- k3: bit-parallel greedy matching + radix top-R ----------
__global__ __launch_bounds__(256) void k3_match(const unsigned long long* __restrict__ prio,
                                                unsigned int* __restrict__ kept) {
  __shared__ unsigned long long pr[4096];     // 32 KB
  __shared__ unsigned int stw[258];
  __shared__ int hist[256];
  __shared__ int wsum[4];
  __shared__ int sh_flag;
  __shared__ int sh_need;
  __shared__ int sh_exact;
  __shared__ unsigned long long sh_prefix;
  __shared__ unsigned long long sh_tmin;
  __shared__ unsigned long long sh_tmax;

  const int tid = threadIdx.x;
  const int b = blockIdx.x;

#pragma unroll
  for (int j = 0; j < 16; ++j) {
    const int e = tid + j * 256;
    pr[e] = (e < 4095) ? prio[(size_t)b * S_ + e] : 0ull;
  }
  if (tid == 0) {
    stw[0] = 0xAAAAAAAAu;
    stw[257] = 0xAAAAAAAAu;
    sh_flag = 0; sh_need = R_; sh_prefix = 0ull;
    sh_exact = 0; sh_tmin = ~0ull; sh_tmax = 0ull;
  }
  stw[1 + tid] = (tid == 255) ? 0x80000000u : 0u;
  __syncthreads();

  unsigned int cl = 0, cr = 0;
#pragma unroll
  for (int j = 0; j < 16; ++j) {
    const int e = tid * 16 + j;
    const unsigned long long pe = pr[e];
    const bool L = (e == 0) || (pe > pr[e - 1]);
    const bool R = (e >= 4094) || (pe > pr[e + 1]);
    cl |= (L ? 1u : 0u) << (2 * j);
    cr |= (R ? 1u : 0u) << (2 * j);
  }

  for (;;) {
    __syncthreads();
    if (tid == 0) sh_flag = 0;
    __syncthreads();
    unsigned int u = stw[1 + tid];
    const unsigned int lw = stw[tid];
    const unsigned int rw = stw[2 + tid];
    const unsigned int linb = (lw >> 30) & 1u;
    const unsigned int loutb = (lw >> 31) & 1u;
    const unsigned int rinb = (rw & 1u) << 30;
    const unsigned int routb = ((rw >> 1) & 1u) << 30;
    bool changed = false;
    for (;;) {
      const unsigned int a = u & 0x55555555u;
      const unsigned int d = (u >> 1) & 0x55555555u;
      const unsigned int lin = (a << 2) | linb;
      const unsigned int lout = (d << 2) | loutb;
      const unsigned int rin = (a >> 2) | rinb;
      const unsigned int rout = (d >> 2) | routb;
      const unsigned int undec = ~(a | d) & 0x55555555u;
      const unsigned int nout = undec & (lin | rin);
      const unsigned int nin = undec & ~lin & ~rin & (lout | cl) & (rout | cr);
      if (!(nin | nout)) break;
      u |= nin | (nout << 1);
      changed = true;
    }
    if (changed) { stw[1 + tid] = u; sh_flag = 1; }
    __syncthreads();
    if (sh_flag == 0) break;
  }

  const unsigned int inw = stw[1 + tid] & 0x55555555u;

  int exitmode = 0;
#pragma unroll 1
  for (int level = 0; level < 8; ++level) {
    const int shift = 56 - 8 * level;
    __syncthreads();
    hist[tid] = 0;
    __syncthreads();
    const unsigned long long pref = sh_prefix;
#pragma unroll
    for (int j = 0; j < 16; ++j) {
      if (!((inw >> (2 * j)) & 1u)) continue;
      const unsigned long long p = pr[tid * 16 + j];
      const bool match = (level == 0) || ((p >> (shift + 8)) == (pref >> (shift + 8)));
      if (match) atomicAdd(&hist[(int)((p >> shift) & 255ull)], 1);
    }
    __syncthreads();
    if (tid < 64) {
      const int lane = tid;
      const int need = sh_need;
      const int h0 = hist[lane * 4 + 0], h1 = hist[lane * 4 + 1];
      const int h2 = hist[lane * 4 + 2], h3 = hist[lane * 4 + 3];
      const int gsum = h0 + h1 + h2 + h3;
      int s = gsum;
#pragma unroll
      for (int off = 1; off < 64; off <<= 1) {
        const int v = __shfl_down(s, off);
        if (lane + off < 64) s += v;
      }
      const int suffAbove = s - gsum;
      if (suffAbove < need && s >= need) {
        const int hh[4] = {h0, h1, h2, h3};
        int cum = suffAbove;
        for (int q = 3; q >= 0; --q) {
          cum += hh[q];
          if (cum >= need) {
            const int need2 = need - (cum - hh[q]);
            sh_prefix = pref | ((unsigned long long)(lane * 4 + q) << shift);
            sh_need = need2;
            if (need2 == hh[q]) sh_exact = 1;       // whole bin selected -> min
            else if (need2 == 1) sh_exact = 2;      // top of bin -> max
            break;
          }
        }
      }
    }
    __syncthreads();
    const int ex = sh_exact;
    if (ex) {
      exitmode = ex;
      const unsigned long long pref2 = sh_prefix;
      unsigned long long best = (ex == 1) ? ~0ull : 0ull;
#pragma unroll
      for (int j = 0; j < 16; ++j) {
        if (!((inw >> (2 * j)) & 1u)) continue;
        const unsigned long long p = pr[tid * 16 + j];
        if ((p >> shift) == (pref2 >> shift))
          best = (ex == 1) ? (best < p ? best : p) : (best > p ? best : p);
      }
#pragma unroll
      for (int off = 1; off < 64; off <<= 1) {
        const unsigned long long o = __shfl_xor(best, off);
        best = (ex == 1) ? (best < o ? best : o) : (best > o ? best : o);
      }
      if ((tid & 63) == 0) {
        if (ex == 1) atomicMin(&sh_tmin, best);
        else atomicMax(&sh_tmax, best);
      }
      __syncthreads();
      break;
    }
  }
  const unsigned long long thresh =
      (exitmode == 1) ? sh_tmin : (exitmode == 2) ? sh_tmax : sh_prefix;
  const unsigned int previnw = stw[tid] & 0x55555555u;

  int c = 0;
  unsigned int kpbits = 0;
#pragma unroll
  for (int j = 0; j < 16; ++j) {
    const int s = tid * 16 + j;
    bool selprev = false;
    if (s > 0) {
      const unsigned int ib =
          (j == 0) ? ((previnw >> 30) & 1u) : ((inw >> (2 * (j - 1))) & 1u);
      selprev = ib && (pr[s - 1] >= thresh);
    }
    if (!selprev) { kpbits |= 1u << j; ++c; }
  }
  const int lane = tid & 63, w = tid >> 6;
  int v = c;
#pragma unroll
  for (int off = 1; off < 64; off <<= 1) {
    const int t2 = __shfl_up(v, off);
    if (lane >= off) v += t2;
  }
  if (lane == 63) wsum[w] = v;
  __syncthreads();
  if (tid == 0) {
    int run = 0;
    for (int q = 0; q < 4; ++q) { const int t3 = wsum[q]; wsum[q] = run; run += t3; }
  }
  __syncthreads();
  int pos = (v - c) + wsum[w];
#pragma unroll
  for (int j = 0; j < 16; ++j) {
    if ((kpbits >> j) & 1u) {
      const int s = tid * 16 + j;
      const unsigned int m =
          (((inw >> (2 * j)) & 1u) && pr[s] >= thresh) ? 0x80000000u : 0u;
      kept[b * SO_ + pos] = (unsigned int)s | m;
      ++pos;
    }
  }
}

// ---------------- k45: fused src + x + pos gather/merge -------------------
// All src/x rows are single-touch (kept rows read as primary, dropped rows
// only as merge partner) => zero reuse => non-temporal everywhere.
__global__ __launch_bounds__(256) void k45_gather(const float* __restrict__ src,
                                                  const float* __restrict__ x,
                                                  const float* __restrict__ gn,
                                                  const int* __restrict__ posid,
                                                  const unsigned int* __restrict__ kept,
                                                  float* __restrict__ outs,
                                                  float* __restrict__ outx,
                                                  float* __restrict__ outpos) {
  const int blk = blockIdx.x;
  const int b = blk / SO_;
  const int j = blk - b * SO_;
  const unsigned int ent = kept[b * SO_ + j];
  const int s = (int)(ent & 0x7FFFFFFFu);
  const bool m = (ent & 0x80000000u) != 0u;
  const size_t rrow = (size_t)b * S_ + s;
  const size_t orow = (size_t)b * SO_ + j;
  const size_t rin = rrow * NO_;
  const size_t rout = orow * NO_;
  const int t = threadIdx.x;

  // src row (16 KB), streaming: non-temporal
#pragma unroll
  for (int it = 0; it < 4; ++it) {
    const int f4 = t + it * 256;
    f4v a = __builtin_nontemporal_load(
        reinterpret_cast<const f4v*>(&src[rin + (size_t)f4 * 4]));
    if (m) {
      const f4v c2 = __builtin_nontemporal_load(
          reinterpret_cast<const f4v*>(&src[rin + NO_ + (size_t)f4 * 4]));
      a += c2;
    }
    __builtin_nontemporal_store(a, reinterpret_cast<f4v*>(&outs[rout + (size_t)f4 * 4]));
  }

  // x row (2 KB) on threads 0..127, also streaming
  if (t < 128) {
    f4v a = __builtin_nontemporal_load(
        reinterpret_cast<const f4v*>(&x[rrow * D_ + t * 4]));
    f4v o;
    if (m) {
      const float w0 = gn[rrow], w1 = gn[rrow + 1];
      const f4v c2 = __builtin_nontemporal_load(
          reinterpret_cast<const f4v*>(&x[(rrow + 1) * D_ + t * 4]));
      const float den = w0 + w1 + EPS_MERGE;
      o.x = (w0 * a.x + w1 * c2.x) / den;
      o.y = (w0 * a.y + w1 * c2.y) / den;
      o.z = (w0 * a.z + w1 * c2.z) / den;
      o.w = (w0 * a.w + w1 * c2.w) / den;
    } else {
      o = a;
    }
    __builtin_nontemporal_store(o, reinterpret_cast<f4v*>(&outx[orow * D_ + t * 4]));
  }
  if (t == 0) outpos[orow] = (float)posid[rrow];
}

extern "C" void kernel_launch(void* const* d_in, const int* in_sizes, int n_in,
                              void* d_out, int out_size, void* d_ws, size_t ws_size,
                              hipStream_t stream) {
  (void)in_sizes; (void)n_in; (void)out_size; (void)ws_size;
  const float* x = (const float*)d_in[0];
  const float* src = (const float*)d_in[1];
  const int* posid = (const int*)d_in[2];
  const float* W = (const float*)d_in[3];

  char* ws = (char*)d_ws;
  float* g = (float*)(ws + WS_G);
  float* gn = (float*)(ws + WS_GN);
  unsigned long long* prio = (unsigned long long*)(ws + WS_KEYS);
  unsigned int* kept = (unsigned int*)(ws + WS_KEPT);

  float* outx = (float*)d_out;
  float* outs = outx + (size_t)B_ * SO_ * D_;
  float* outpos = outs + (size_t)B_ * SO_ * NO_;

  hipLaunchKernelGGL(k1_proj, dim3(256), dim3(256), 0, stream, x, W, g, gn);
  hipLaunchKernelGGL(k2_sim, dim3((B_ * (S_ - 1) + 3) / 4), dim3(256), 0, stream, g, gn, prio);
  hipLaunchKernelGGL(k3_match, dim3(B_), dim3(256), 0, stream, prio, kept);
  hipLaunchKernelGGL(k45_gather, dim3(B_ * SO_), dim3(256), 0, stream, src, x, gn,
                     posid, kept, outs, outx, outpos);
}

// Round 7
// 225.350 us; speedup vs baseline: 1.6160x; 1.0530x over previous
//
#include <hip/hip_runtime.h>
#include <hip/hip_bf16.h>
#include <stdint.h>

#define B_ 8
#define S_ 4096
#define D_ 512
#define G_ 64
#define R_ 1024
#define NO_ 4096
#define SO_ 3072   /* S_ - R_ */
#define EPS_MERGE 1e-8f
#define EPS_NORM 1e-12f

typedef float f4v __attribute__((ext_vector_type(4)));

// workspace byte offsets
#define WS_G     0ull                 // g: 32768*64 f32   = 8388608 B
#define WS_GN    8388608ull           // gn: 32768 f32     = 131072 B
#define WS_KEYS  8519680ull           // prio: 8*4096 u64  = 262144 B
#define WS_KEPT  8781824ull           // kept: 8*3072 u32  = 98304 B

// ---------------- k1: g = x @ W^T  (M=32768, N=64, K=512) + row norms ----
// 512 blocks x 256 threads, 64 rows/block (2 blocks/CU -> 8 waves/CU TLP).
// Thread = 4 rows x 4 g. Register prefetch of chunk kc+1 during FMA of kc.
// Per-(row,g) accumulation order (kc 0..15, k 0..31) identical to all
// previous versions -> bitwise-identical g/gn.
__global__ __launch_bounds__(256) void k1_proj(const float* __restrict__ x,
                                               const float* __restrict__ W,
                                               float* __restrict__ g,
                                               float* __restrict__ gn) {
  __shared__ float xs[32][68];
  __shared__ float wc[32][68];
  const int tid = threadIdx.x;
  const int gt  = tid & 15;
  const int rt  = tid >> 4;
  const int rb  = blockIdx.x * 64;
  const int g0  = gt * 4;
  const int r0  = rt * 4;
  const int kq4 = (tid & 7) * 4;   // k sub-offset this thread stages
  const int rl0 = tid >> 3;        // row/g staged (+ i*32)

  const float* xp[2];
  const float* wp[2];
#pragma unroll
  for (int i = 0; i < 2; ++i)
    xp[i] = &x[(size_t)(rb + rl0 + i * 32) * D_ + kq4];
#pragma unroll
  for (int i = 0; i < 2; ++i)
    wp[i] = &W[(size_t)(rl0 + i * 32) * D_ + kq4];

  float4 px[2], pw[2];
#pragma unroll
  for (int i = 0; i < 2; ++i) px[i] = *reinterpret_cast<const float4*>(xp[i]);
#pragma unroll
  for (int i = 0; i < 2; ++i) pw[i] = *reinterpret_cast<const float4*>(wp[i]);

  float acc[4][4];
#pragma unroll
  for (int r = 0; r < 4; ++r)
#pragma unroll
    for (int j = 0; j < 4; ++j) acc[r][j] = 0.f;

  for (int kc = 0; kc < 16; ++kc) {
    __syncthreads();   // previous chunk fully consumed
#pragma unroll
    for (int i = 0; i < 2; ++i) {
      const int rl = rl0 + i * 32;
      xs[kq4 + 0][rl] = px[i].x;
      xs[kq4 + 1][rl] = px[i].y;
      xs[kq4 + 2][rl] = px[i].z;
      xs[kq4 + 3][rl] = px[i].w;
    }
#pragma unroll
    for (int i = 0; i < 2; ++i) {
      const int gg = rl0 + i * 32;
      wc[kq4 + 0][gg] = pw[i].x;
      wc[kq4 + 1][gg] = pw[i].y;
      wc[kq4 + 2][gg] = pw[i].z;
      wc[kq4 + 3][gg] = pw[i].w;
    }
    if (kc < 15) {
      const int off = (kc + 1) * 32;
#pragma unroll
      for (int i = 0; i < 2; ++i)
        px[i] = *reinterpret_cast<const float4*>(xp[i] + off);
#pragma unroll
      for (int i = 0; i < 2; ++i)
        pw[i] = *reinterpret_cast<const float4*>(wp[i] + off);
    }
    __syncthreads();   // chunk kc visible in LDS
#pragma unroll
    for (int k = 0; k < 32; ++k) {
      const float4 wv = *reinterpret_cast<const float4*>(&wc[k][g0]);
      const float4 xa = *reinterpret_cast<const float4*>(&xs[k][r0]);
      const float xr[4] = {xa.x, xa.y, xa.z, xa.w};
#pragma unroll
      for (int r = 0; r < 4; ++r) {
        acc[r][0] = fmaf(xr[r], wv.x, acc[r][0]);
        acc[r][1] = fmaf(xr[r], wv.y, acc[r][1]);
        acc[r][2] = fmaf(xr[r], wv.z, acc[r][2]);
        acc[r][3] = fmaf(xr[r], wv.w, acc[r][3]);
      }
    }
  }
#pragma unroll
  for (int r = 0; r < 4; ++r) {
    const int row = rb + r0 + r;
    float4 v;
    v.x = acc[r][0]; v.y = acc[r][1]; v.z = acc[r][2]; v.w = acc[r][3];
    *reinterpret_cast<float4*>(&g[(size_t)row * G_ + g0]) = v;
    float ss = v.x * v.x + v.y * v.y + v.z * v.z + v.w * v.w;
    ss += __shfl_xor(ss, 1);
    ss += __shfl_xor(ss, 2);
    ss += __shfl_xor(ss, 4);
    ss += __shfl_xor(ss, 8);
    if (gt == 0) gn[row] = sqrtf(ss);
  }
}

// ---------------- k2: sim -> priority key (one wave per edge) -------------
// prio[e] = mono(sim) << 32 | (4095 - e): higher = earlier in greedy order.
__global__ __launch_bounds__(256) void k2_sim(const float* __restrict__ g,
                                              const float* __restrict__ gn,
                                              unsigned long long* __restrict__ prio) {
  const int wid = blockIdx.x * 4 + (threadIdx.x >> 6);
  const int lane = threadIdx.x & 63;
  if (wid >= B_ * (S_ - 1)) return;
  const int b = wid / (S_ - 1);
  const int e = wid - b * (S_ - 1);
  const size_t row = (size_t)b * S_ + e;
  const float a = g[row * G_ + lane];
  const float c = g[(row + 1) * G_ + lane];
  float p = a * c;
  p += __shfl_xor(p, 1);
  p += __shfl_xor(p, 2);
  p += __shfl_xor(p, 4);
  p += __shfl_xor(p, 8);
  p += __shfl_xor(p, 16);
  p += __shfl_xor(p, 32);
  if (lane == 0) {
    const float n0 = fmaxf(gn[row], EPS_NORM);
    const float n1 = fmaxf(gn[row + 1], EPS_NORM);
    const float sim = p / (n0 * n1);
    const unsigned int u = __float_as_uint(sim);
    const unsigned int m = (u & 0x80000000u) ? ~u : (u | 0x80000000u);
    prio[(size_t)b * S_ + e] =
        ((unsigned long long)m << 32) | (unsigned long long)(unsigned int)(4095 - e);
  }
}

// ---------------- k3: bit-parallel greedy matching + radix top-R ----------
__global__ __launch_bounds__(256) void k3_match(const unsigned long long* __restrict__ prio,
                                                unsigned int* __restrict__ kept) {
  __shared__ unsigned long long pr[4096];     // 32 KB
  __shared__ unsigned int stw[258];
  __shared__ int hist[256];
  __shared__ int wsum[4];
  __shared__ int sh_flag;
  __shared__ int sh_need;
  __shared__ int sh_exact;
  __shared__ unsigned long long sh_prefix;
  __shared__ unsigned long long sh_tmin;
  __shared__ unsigned long long sh_tmax;

  const int tid = threadIdx.x;
  const int b = blockIdx.x;

#pragma unroll
  for (int j = 0; j < 16; ++j) {
    const int e = tid + j * 256;
    pr[e] = (e < 4095) ? prio[(size_t)b * S_ + e] : 0ull;
  }
  if (tid == 0) {
    stw[0] = 0xAAAAAAAAu;
    stw[257] = 0xAAAAAAAAu;
    sh_flag = 0; sh_need = R_; sh_prefix = 0ull;
    sh_exact = 0; sh_tmin = ~0ull; sh_tmax = 0ull;
  }
  stw[1 + tid] = (tid == 255) ? 0x80000000u : 0u;
  __syncthreads();

  unsigned int cl = 0, cr = 0;
#pragma unroll
  for (int j = 0; j < 16; ++j) {
    const int e = tid * 16 + j;
    const unsigned long long pe = pr[e];
    const bool L = (e == 0) || (pe > pr[e - 1]);
    const bool R = (e >= 4094) || (pe > pr[e + 1]);
    cl |= (L ? 1u : 0u) << (2 * j);
    cr |= (R ? 1u : 0u) << (2 * j);
  }

  for (;;) {
    __syncthreads();
    if (tid == 0) sh_flag = 0;
    __syncthreads();
    unsigned int u = stw[1 + tid];
    const unsigned int lw = stw[tid];
    const unsigned int rw = stw[2 + tid];
    const unsigned int linb = (lw >> 30) & 1u;
    const unsigned int loutb = (lw >> 31) & 1u;
    const unsigned int rinb = (rw & 1u) << 30;
    const unsigned int routb = ((rw >> 1) & 1u) << 30;
    bool changed = false;
    for (;;) {
      const unsigned int a = u & 0x55555555u;
      const unsigned int d = (u >> 1) & 0x55555555u;
      const unsigned int lin = (a << 2) | linb;
      const unsigned int lout = (d << 2) | loutb;
      const unsigned int rin = (a >> 2) | rinb;
      const unsigned int rout = (d >> 2) | routb;
      const unsigned int undec = ~(a | d) & 0x55555555u;
      const unsigned int nout = undec & (lin | rin);
      const unsigned int nin = undec & ~lin & ~rin & (lout | cl) & (rout | cr);
      if (!(nin | nout)) break;
      u |= nin | (nout << 1);
      changed = true;
    }
    if (changed) { stw[1 + tid] = u; sh_flag = 1; }
    __syncthreads();
    if (sh_flag == 0) break;
  }

  const unsigned int inw = stw[1 + tid] & 0x55555555u;

  int exitmode = 0;
#pragma unroll 1
  for (int level = 0; level < 8; ++level) {
    const int shift = 56 - 8 * level;
    __syncthreads();
    hist[tid] = 0;
    __syncthreads();
    const unsigned long long pref = sh_prefix;
#pragma unroll
    for (int j = 0; j < 16; ++j) {
      if (!((inw >> (2 * j)) & 1u)) continue;
      const unsigned long long p = pr[tid * 16 + j];
      const bool match = (level == 0) || ((p >> (shift + 8)) == (pref >> (shift + 8)));
      if (match) atomicAdd(&hist[(int)((p >> shift) & 255ull)], 1);
    }
    __syncthreads();
    if (tid < 64) {
      const int lane = tid;
      const int need = sh_need;
      const int h0 = hist[lane * 4 + 0], h1 = hist[lane * 4 + 1];
      const int h2 = hist[lane * 4 + 2], h3 = hist[lane * 4 + 3];
      const int gsum = h0 + h1 + h2 + h3;
      int s = gsum;
#pragma unroll
      for (int off = 1; off < 64; off <<= 1) {
        const int v = __shfl_down(s, off);
        if (lane + off < 64) s += v;
      }
      const int suffAbove = s - gsum;
      if (suffAbove < need && s >= need) {
        const int hh[4] = {h0, h1, h2, h3};
        int cum = suffAbove;
        for (int q = 3; q >= 0; --q) {
          cum += hh[q];
          if (cum >= need) {
            const int need2 = need - (cum - hh[q]);
            sh_prefix = pref | ((unsigned long long)(lane * 4 + q) << shift);
            sh_need = need2;
            if (need2 == hh[q]) sh_exact = 1;       // whole bin selected -> min
            else if (need2 == 1) sh_exact = 2;      // top of bin -> max
            break;
          }
        }
      }
    }
    __syncthreads();
    const int ex = sh_exact;
    if (ex) {
      exitmode = ex;
      const unsigned long long pref2 = sh_prefix;
      unsigned long long best = (ex == 1) ? ~0ull : 0ull;
#pragma unroll
      for (int j = 0; j < 16; ++j) {
        if (!((inw >> (2 * j)) & 1u)) continue;
        const unsigned long long p = pr[tid * 16 + j];
        if ((p >> shift) == (pref2 >> shift))
          best = (ex == 1) ? (best < p ? best : p) : (best > p ? best : p);
      }
#pragma unroll
      for (int off = 1; off < 64; off <<= 1) {
        const unsigned long long o = __shfl_xor(best, off);
        best = (ex == 1) ? (best < o ? best : o) : (best > o ? best : o);
      }
      if ((tid & 63) == 0) {
        if (ex == 1) atomicMin(&sh_tmin, best);
        else atomicMax(&sh_tmax, best);
      }
      __syncthreads();
      break;
    }
  }
  const unsigned long long thresh =
      (exitmode == 1) ? sh_tmin : (exitmode == 2) ? sh_tmax : sh_prefix;
  const unsigned int previnw = stw[tid] & 0x55555555u;

  int c = 0;
  unsigned int kpbits = 0;
#pragma unroll
  for (int j = 0; j < 16; ++j) {
    const int s = tid * 16 + j;
    bool selprev = false;
    if (s > 0) {
      const unsigned int ib =
          (j == 0) ? ((previnw >> 30) & 1u) : ((inw >> (2 * (j - 1))) & 1u);
      selprev = ib && (pr[s - 1] >= thresh);
    }
    if (!selprev) { kpbits |= 1u << j; ++c; }
  }
  const int lane = tid & 63, w = tid >> 6;
  int v = c;
#pragma unroll
  for (int off = 1; off < 64; off <<= 1) {
    const int t2 = __shfl_up(v, off);
    if (lane >= off) v += t2;
  }
  if (lane == 63) wsum[w] = v;
  __syncthreads();
  if (tid == 0) {
    int run = 0;
    for (int q = 0; q < 4; ++q) { const int t3 = wsum[q]; wsum[q] = run; run += t3; }
  }
  __syncthreads();
  int pos = (v - c) + wsum[w];
#pragma unroll
  for (int j = 0; j < 16; ++j) {
    if ((kpbits >> j) & 1u) {
      const int s = tid * 16 + j;
      const unsigned int m =
          (((inw >> (2 * j)) & 1u) && pr[s] >= thresh) ? 0x80000000u : 0u;
      kept[b * SO_ + pos] = (unsigned int)s | m;
      ++pos;
    }
  }
}

// ---------------- k45: fused src + x + pos gather/merge -------------------
// src: single-touch 512MB stream > L3 -> non-temporal.
// x: re-read after k1 (likely L2/L3-resident) -> NORMAL loads (NT here
// regressed +8.5us in round 6).
__global__ __launch_bounds__(256) void k45_gather(const float* __restrict__ src,
                                                  const float* __restrict__ x,
                                                  const float* __restrict__ gn,
                                                  const int* __restrict__ posid,
                                                  const unsigned int* __restrict__ kept,
                                                  float* __restrict__ outs,
                                                  float* __restrict__ outx,
                                                  float* __restrict__ outpos) {
  const int blk = blockIdx.x;
  const int b = blk / SO_;
  const int j = blk - b * SO_;
  const unsigned int ent = kept[b * SO_ + j];
  const int s = (int)(ent & 0x7FFFFFFFu);
  const bool m = (ent & 0x80000000u) != 0u;
  const size_t rrow = (size_t)b * S_ + s;
  const size_t orow = (size_t)b * SO_ + j;
  const size_t rin = rrow * NO_;
  const size_t rout = orow * NO_;
  const int t = threadIdx.x;

  // src row (16 KB), streaming: non-temporal
#pragma unroll
  for (int it = 0; it < 4; ++it) {
    const int f4 = t + it * 256;
    f4v a = __builtin_nontemporal_load(
        reinterpret_cast<const f4v*>(&src[rin + (size_t)f4 * 4]));
    if (m) {
      const f4v c2 = __builtin_nontemporal_load(
          reinterpret_cast<const f4v*>(&src[rin + NO_ + (size_t)f4 * 4]));
      a += c2;
    }
    __builtin_nontemporal_store(a, reinterpret_cast<f4v*>(&outs[rout + (size_t)f4 * 4]));
  }

  // x row (2 KB) on threads 0..127 (normal loads: L3 reuse from k1)
  if (t < 128) {
    float4 a = *reinterpret_cast<const float4*>(&x[rrow * D_ + t * 4]);
    float4 o;
    if (m) {
      const float w0 = gn[rrow], w1 = gn[rrow + 1];
      const float4 c2 = *reinterpret_cast<const float4*>(&x[(rrow + 1) * D_ + t * 4]);
      const float den = w0 + w1 + EPS_MERGE;
      o.x = (w0 * a.x + w1 * c2.x) / den;
      o.y = (w0 * a.y + w1 * c2.y) / den;
      o.z = (w0 * a.z + w1 * c2.z) / den;
      o.w = (w0 * a.w + w1 * c2.w) / den;
    } else {
      o = a;
    }
    *reinterpret_cast<float4*>(&outx[orow * D_ + t * 4]) = o;
  }
  if (t == 0) outpos[orow] = (float)posid[rrow];
}

extern "C" void kernel_launch(void* const* d_in, const int* in_sizes, int n_in,
                              void* d_out, int out_size, void* d_ws, size_t ws_size,
                              hipStream_t stream) {
  (void)in_sizes; (void)n_in; (void)out_size; (void)ws_size;
  const float* x = (const float*)d_in[0];
  const float* src = (const float*)d_in[1];
  const int* posid = (const int*)d_in[2];
  const float* W = (const float*)d_in[3];

  char* ws = (char*)d_ws;
  float* g = (float*)(ws + WS_G);
  float* gn = (float*)(ws + WS_GN);
  unsigned long long* prio = (unsigned long long*)(ws + WS_KEYS);
  unsigned int* kept = (unsigned int*)(ws + WS_KEPT);

  float* outx = (float*)d_out;
  float* outs = outx + (size_t)B_ * SO_ * D_;
  float* outpos = outs + (size_t)B_ * SO_ * NO_;

  hipLaunchKernelGGL(k1_proj, dim3(512), dim3(256), 0, stream, x, W, g, gn);
  hipLaunchKernelGGL(k2_sim, dim3((B_ * (S_ - 1) + 3) / 4), dim3(256), 0, stream, g, gn, prio);
  hipLaunchKernelGGL(k3_match, dim3(B_), dim3(256), 0, stream, prio, kept);
  hipLaunchKernelGGL(k45_gather, dim3(B_ * SO_), dim3(256), 0, stream, src, x, gn,
                     posid, kept, outs, outx, outpos);
}

// Round 8
// 225.087 us; speedup vs baseline: 1.6179x; 1.0012x over previous
//
#include <hip/hip_runtime.h>
#include <hip/hip_bf16.h>
#include <stdint.h>

#define B_ 8
#define S_ 4096
#define D_ 512
#define G_ 64
#define R_ 1024
#define NO_ 4096
#define SO_ 3072   /* S_ - R_ */
#define EPS_MERGE 1e-8f
#define EPS_NORM 1e-12f

typedef float f4v __attribute__((ext_vector_type(4)));

// workspace byte offsets
#define WS_G     0ull                 // g: 32768*64 f32   = 8388608 B
#define WS_GN    8388608ull           // gn: 32768 f32     = 131072 B
#define WS_KEYS  8519680ull           // prio: 8*4096 u64  = 262144 B
#define WS_KEPT  8781824ull           // kept: 8*3072 u32  = 98304 B

// ---------------- k1: g = x @ W^T  (M=32768, N=64, K=512) + row norms ----
// 512 blocks x 256 threads, 64 rows/block (2 blocks/CU -> 8 waves/CU TLP).
__global__ __launch_bounds__(256) void k1_proj(const float* __restrict__ x,
                                               const float* __restrict__ W,
                                               float* __restrict__ g,
                                               float* __restrict__ gn) {
  __shared__ float xs[32][68];
  __shared__ float wc[32][68];
  const int tid = threadIdx.x;
  const int gt  = tid & 15;
  const int rt  = tid >> 4;
  const int rb  = blockIdx.x * 64;
  const int g0  = gt * 4;
  const int r0  = rt * 4;
  const int kq4 = (tid & 7) * 4;
  const int rl0 = tid >> 3;

  const float* xp[2];
  const float* wp[2];
#pragma unroll
  for (int i = 0; i < 2; ++i)
    xp[i] = &x[(size_t)(rb + rl0 + i * 32) * D_ + kq4];
#pragma unroll
  for (int i = 0; i < 2; ++i)
    wp[i] = &W[(size_t)(rl0 + i * 32) * D_ + kq4];

  float4 px[2], pw[2];
#pragma unroll
  for (int i = 0; i < 2; ++i) px[i] = *reinterpret_cast<const float4*>(xp[i]);
#pragma unroll
  for (int i = 0; i < 2; ++i) pw[i] = *reinterpret_cast<const float4*>(wp[i]);

  float acc[4][4];
#pragma unroll
  for (int r = 0; r < 4; ++r)
#pragma unroll
    for (int j = 0; j < 4; ++j) acc[r][j] = 0.f;

  for (int kc = 0; kc < 16; ++kc) {
    __syncthreads();
#pragma unroll
    for (int i = 0; i < 2; ++i) {
      const int rl = rl0 + i * 32;
      xs[kq4 + 0][rl] = px[i].x;
      xs[kq4 + 1][rl] = px[i].y;
      xs[kq4 + 2][rl] = px[i].z;
      xs[kq4 + 3][rl] = px[i].w;
    }
#pragma unroll
    for (int i = 0; i < 2; ++i) {
      const int gg = rl0 + i * 32;
      wc[kq4 + 0][gg] = pw[i].x;
      wc[kq4 + 1][gg] = pw[i].y;
      wc[kq4 + 2][gg] = pw[i].z;
      wc[kq4 + 3][gg] = pw[i].w;
    }
    if (kc < 15) {
      const int off = (kc + 1) * 32;
#pragma unroll
      for (int i = 0; i < 2; ++i)
        px[i] = *reinterpret_cast<const float4*>(xp[i] + off);
#pragma unroll
      for (int i = 0; i < 2; ++i)
        pw[i] = *reinterpret_cast<const float4*>(wp[i] + off);
    }
    __syncthreads();
#pragma unroll
    for (int k = 0; k < 32; ++k) {
      const float4 wv = *reinterpret_cast<const float4*>(&wc[k][g0]);
      const float4 xa = *reinterpret_cast<const float4*>(&xs[k][r0]);
      const float xr[4] = {xa.x, xa.y, xa.z, xa.w};
#pragma unroll
      for (int r = 0; r < 4; ++r) {
        acc[r][0] = fmaf(xr[r], wv.x, acc[r][0]);
        acc[r][1] = fmaf(xr[r], wv.y, acc[r][1]);
        acc[r][2] = fmaf(xr[r], wv.z, acc[r][2]);
        acc[r][3] = fmaf(xr[r], wv.w, acc[r][3]);
      }
    }
  }
#pragma unroll
  for (int r = 0; r < 4; ++r) {
    const int row = rb + r0 + r;
    float4 v;
    v.x = acc[r][0]; v.y = acc[r][1]; v.z = acc[r][2]; v.w = acc[r][3];
    *reinterpret_cast<float4*>(&g[(size_t)row * G_ + g0]) = v;
    float ss = v.x * v.x + v.y * v.y + v.z * v.z + v.w * v.w;
    ss += __shfl_xor(ss, 1);
    ss += __shfl_xor(ss, 2);
    ss += __shfl_xor(ss, 4);
    ss += __shfl_xor(ss, 8);
    if (gt == 0) gn[row] = sqrtf(ss);
  }
}

// ---------------- k2: sim -> priority key (one wave per edge) -------------
__global__ __launch_bounds__(256) void k2_sim(const float* __restrict__ g,
                                              const float* __restrict__ gn,
                                              unsigned long long* __restrict__ prio) {
  const int wid = blockIdx.x * 4 + (threadIdx.x >> 6);
  const int lane = threadIdx.x & 63;
  if (wid >= B_ * (S_ - 1)) return;
  const int b = wid / (S_ - 1);
  const int e = wid - b * (S_ - 1);
  const size_t row = (size_t)b * S_ + e;
  const float a = g[row * G_ + lane];
  const float c = g[(row + 1) * G_ + lane];
  float p = a * c;
  p += __shfl_xor(p, 1);
  p += __shfl_xor(p, 2);
  p += __shfl_xor(p, 4);
  p += __shfl_xor(p, 8);
  p += __shfl_xor(p, 16);
  p += __shfl_xor(p, 32);
  if (lane == 0) {
    const float n0 = fmaxf(gn[row], EPS_NORM);
    const float n1 = fmaxf(gn[row + 1], EPS_NORM);
    const float sim = p / (n0 * n1);
    const unsigned int u = __float_as_uint(sim);
    const unsigned int m = (u & 0x80000000u) ? ~u : (u | 0x80000000u);
    prio[(size_t)b * S_ + e] =
        ((unsigned long long)m << 32) | (unsigned long long)(unsigned int)(4095 - e);
  }
}

// ---------------- k3: bit-parallel greedy matching + radix top-R ----------
// Barrier-lean: 1 barrier/matching-round (round-counter flag, monotone
// chaotic iteration tolerates stale/torn reads), 2 barriers/radix-level
// (ping-pong histogram zeroed by idle threads during the select phase).
// All arithmetic identical to round 7 -> bit-identical selection.
__global__ __launch_bounds__(256) void k3_match(const unsigned long long* __restrict__ prio,
                                                unsigned int* __restrict__ kept) {
  __shared__ unsigned long long pr[4096];     // 32 KB
  __shared__ unsigned int stw[258];
  __shared__ int hist[2][256];
  __shared__ int wsum[4];
  __shared__ int sh_flag;
  __shared__ int sh_need;
  __shared__ int sh_exact;
  __shared__ unsigned long long sh_prefix;
  __shared__ unsigned long long sh_tmin;
  __shared__ unsigned long long sh_tmax;

  const int tid = threadIdx.x;
  const int b = blockIdx.x;

#pragma unroll
  for (int j = 0; j < 16; ++j) {
    const int e = tid + j * 256;
    pr[e] = (e < 4095) ? prio[(size_t)b * S_ + e] : 0ull;
  }
  if (tid == 0) {
    stw[0] = 0xAAAAAAAAu;
    stw[257] = 0xAAAAAAAAu;
    sh_flag = -1; sh_need = R_; sh_prefix = 0ull;
    sh_exact = 0; sh_tmin = ~0ull; sh_tmax = 0ull;
  }
  hist[0][tid] = 0;
  hist[1][tid] = 0;
  stw[1 + tid] = (tid == 255) ? 0x80000000u : 0u;
  __syncthreads();

  unsigned int cl = 0, cr = 0;
#pragma unroll
  for (int j = 0; j < 16; ++j) {
    const int e = tid * 16 + j;
    const unsigned long long pe = pr[e];
    const bool L = (e == 0) || (pe > pr[e - 1]);
    const bool R = (e >= 4094) || (pe > pr[e + 1]);
    cl |= (L ? 1u : 0u) << (2 * j);
    cr |= (R ? 1u : 0u) << (2 * j);
  }

  // ---- matching rounds: ONE barrier per round ----
  for (int r = 0;; ++r) {
    unsigned int u = stw[1 + tid];
    const unsigned int lw = stw[tid];
    const unsigned int rw = stw[2 + tid];
    const unsigned int linb = (lw >> 30) & 1u;
    const unsigned int loutb = (lw >> 31) & 1u;
    const unsigned int rinb = (rw & 1u) << 30;
    const unsigned int routb = ((rw >> 1) & 1u) << 30;
    bool changed = false;
    for (;;) {
      const unsigned int a = u & 0x55555555u;
      const unsigned int d = (u >> 1) & 0x55555555u;
      const unsigned int lin = (a << 2) | linb;
      const unsigned int lout = (d << 2) | loutb;
      const unsigned int rin = (a >> 2) | rinb;
      const unsigned int rout = (d >> 2) | routb;
      const unsigned int undec = ~(a | d) & 0x55555555u;
      const unsigned int nout = undec & (lin | rin);
      const unsigned int nin = undec & ~lin & ~rin & (lout | cl) & (rout | cr);
      if (!(nin | nout)) break;
      u |= nin | (nout << 1);
      changed = true;
    }
    if (changed) { stw[1 + tid] = u; sh_flag = r; }  // benign same-value race
    __syncthreads();
    if (sh_flag != r) break;   // no thread changed in round r
  }

  const unsigned int inw = stw[1 + tid] & 0x55555555u;
  const unsigned int previnw = stw[tid] & 0x55555555u;

  // ---- radix select: TWO barriers per level (ping-pong hist) ----
  int exitmode = 0;
#pragma unroll 1
  for (int level = 0; level < 8; ++level) {
    const int shift = 56 - 8 * level;
    const int cur = level & 1;
    const unsigned long long pref = sh_prefix;
#pragma unroll
    for (int j = 0; j < 16; ++j) {
      if (!((inw >> (2 * j)) & 1u)) continue;
      const unsigned long long p = pr[tid * 16 + j];
      const bool match = (level == 0) || ((p >> (shift + 8)) == (pref >> (shift + 8)));
      if (match) atomicAdd(&hist[cur][(int)((p >> shift) & 255ull)], 1);
    }
    __syncthreads();   // counts visible
    if (tid < 64) {
      const int lane = tid;
      const int need = sh_need;
      const int h0 = hist[cur][lane * 4 + 0], h1 = hist[cur][lane * 4 + 1];
      const int h2 = hist[cur][lane * 4 + 2], h3 = hist[cur][lane * 4 + 3];
      const int gsum = h0 + h1 + h2 + h3;
      int s = gsum;
#pragma unroll
      for (int off = 1; off < 64; off <<= 1) {
        const int v = __shfl_down(s, off);
        if (lane + off < 64) s += v;
      }
      const int suffAbove = s - gsum;
      if (suffAbove < need && s >= need) {  // unique lane
        const int hh[4] = {h0, h1, h2, h3};
        int cum = suffAbove;
        for (int q = 3; q >= 0; --q) {
          cum += hh[q];
          if (cum >= need) {
            const int need2 = need - (cum - hh[q]);
            sh_prefix = pref | ((unsigned long long)(lane * 4 + q) << shift);
            sh_need = need2;
            if (need2 == hh[q]) sh_exact = 1;       // whole bin -> min of bin
            else if (need2 == 1) sh_exact = 2;      // top of bin -> max of bin
            break;
          }
        }
      }
    } else {
      // zero next level's histogram while lanes 0..63 select
      const int z = tid - 64;
      hist[cur ^ 1][z] = 0;
      if (z < 64) hist[cur ^ 1][z + 192] = 0;
    }
    __syncthreads();   // select + zeroing visible
    const int ex = sh_exact;
    if (ex) {
      exitmode = ex;
      const unsigned long long pref2 = sh_prefix;
      unsigned long long best = (ex == 1) ? ~0ull : 0ull;
#pragma unroll
      for (int j = 0; j < 16; ++j) {
        if (!((inw >> (2 * j)) & 1u)) continue;
        const unsigned long long p = pr[tid * 16 + j];
        if ((p >> shift) == (pref2 >> shift))
          best = (ex == 1) ? (best < p ? best : p) : (best > p ? best : p);
      }
#pragma unroll
      for (int off = 1; off < 64; off <<= 1) {
        const unsigned long long o = __shfl_xor(best, off);
        best = (ex == 1) ? (best < o ? best : o) : (best > o ? best : o);
      }
      if ((tid & 63) == 0) {
        if (ex == 1) atomicMin(&sh_tmin, best);
        else atomicMax(&sh_tmax, best);
      }
      __syncthreads();
      break;
    }
  }
  const unsigned long long thresh =
      (exitmode == 1) ? sh_tmin : (exitmode == 2) ? sh_tmax : sh_prefix;

  // ---- compaction: keep[s] = !(s>0 && sel[s-1]); stable order ----
  int c = 0;
  unsigned int kpbits = 0;
#pragma unroll
  for (int j = 0; j < 16; ++j) {
    const int s = tid * 16 + j;
    bool selprev = false;
    if (s > 0) {
      const unsigned int ib =
          (j == 0) ? ((previnw >> 30) & 1u) : ((inw >> (2 * (j - 1))) & 1u);
      selprev = ib && (pr[s - 1] >= thresh);
    }
    if (!selprev) { kpbits |= 1u << j; ++c; }
  }
  const int lane = tid & 63, w = tid >> 6;
  int v = c;
#pragma unroll
  for (int off = 1; off < 64; off <<= 1) {
    const int t2 = __shfl_up(v, off);
    if (lane >= off) v += t2;
  }
  if (lane == 63) wsum[w] = v;
  __syncthreads();
  if (tid == 0) {
    int run = 0;
    for (int q = 0; q < 4; ++q) { const int t3 = wsum[q]; wsum[q] = run; run += t3; }
  }
  __syncthreads();
  int pos = (v - c) + wsum[w];
#pragma unroll
  for (int j = 0; j < 16; ++j) {
    if ((kpbits >> j) & 1u) {
      const int s = tid * 16 + j;
      const unsigned int m =
          (((inw >> (2 * j)) & 1u) && pr[s] >= thresh) ? 0x80000000u : 0u;
      kept[b * SO_ + pos] = (unsigned int)s | m;
      ++pos;
    }
  }
}

// ---------------- k45: fused src + x + pos gather/merge -------------------
// src: single-touch 512MB stream > L3 -> non-temporal.
// x: re-read after k1 (L2/L3-resident) -> NORMAL loads (NT regressed r6).
__global__ __launch_bounds__(256) void k45_gather(const float* __restrict__ src,
                                                  const float* __restrict__ x,
                                                  const float* __restrict__ gn,
                                                  const int* __restrict__ posid,
                                                  const unsigned int* __restrict__ kept,
                                                  float* __restrict__ outs,
                                                  float* __restrict__ outx,
                                                  float* __restrict__ outpos) {
  const int blk = blockIdx.x;
  const int b = blk / SO_;
  const int j = blk - b * SO_;
  const unsigned int ent = kept[b * SO_ + j];
  const int s = (int)(ent & 0x7FFFFFFFu);
  const bool m = (ent & 0x80000000u) != 0u;
  const size_t rrow = (size_t)b * S_ + s;
  const size_t orow = (size_t)b * SO_ + j;
  const size_t rin = rrow * NO_;
  const size_t rout = orow * NO_;
  const int t = threadIdx.x;

#pragma unroll
  for (int it = 0; it < 4; ++it) {
    const int f4 = t + it * 256;
    f4v a = __builtin_nontemporal_load(
        reinterpret_cast<const f4v*>(&src[rin + (size_t)f4 * 4]));
    if (m) {
      const f4v c2 = __builtin_nontemporal_load(
          reinterpret_cast<const f4v*>(&src[rin + NO_ + (size_t)f4 * 4]));
      a += c2;
    }
    __builtin_nontemporal_store(a, reinterpret_cast<f4v*>(&outs[rout + (size_t)f4 * 4]));
  }

  if (t < 128) {
    float4 a = *reinterpret_cast<const float4*>(&x[rrow * D_ + t * 4]);
    float4 o;
    if (m) {
      const float w0 = gn[rrow], w1 = gn[rrow + 1];
      const float4 c2 = *reinterpret_cast<const float4*>(&x[(rrow + 1) * D_ + t * 4]);
      const float den = w0 + w1 + EPS_MERGE;
      o.x = (w0 * a.x + w1 * c2.x) / den;
      o.y = (w0 * a.y + w1 * c2.y) / den;
      o.z = (w0 * a.z + w1 * c2.z) / den;
      o.w = (w0 * a.w + w1 * c2.w) / den;
    } else {
      o = a;
    }
    *reinterpret_cast<float4*>(&outx[orow * D_ + t * 4]) = o;
  }
  if (t == 0) outpos[orow] = (float)posid[rrow];
}

extern "C" void kernel_launch(void* const* d_in, const int* in_sizes, int n_in,
                              void* d_out, int out_size, void* d_ws, size_t ws_size,
                              hipStream_t stream) {
  (void)in_sizes; (void)n_in; (void)out_size; (void)ws_size;
  const float* x = (const float*)d_in[0];
  const float* src = (const float*)d_in[1];
  const int* posid = (const int*)d_in[2];
  const float* W = (const float*)d_in[3];

  char* ws = (char*)d_ws;
  float* g = (float*)(ws + WS_G);
  float* gn = (float*)(ws + WS_GN);
  unsigned long long* prio = (unsigned long long*)(ws + WS_KEYS);
  unsigned int* kept = (unsigned int*)(ws + WS_KEPT);

  float* outx = (float*)d_out;
  float* outs = outx + (size_t)B_ * SO_ * D_;
  float* outpos = outs + (size_t)B_ * SO_ * NO_;

  hipLaunchKernelGGL(k1_proj, dim3(512), dim3(256), 0, stream, x, W, g, gn);
  hipLaunchKernelGGL(k2_sim, dim3((B_ * (S_ - 1) + 3) / 4), dim3(256), 0, stream, g, gn, prio);
  hipLaunchKernelGGL(k3_match, dim3(B_), dim3(256), 0, stream, prio, kept);
  hipLaunchKernelGGL(k45_gather, dim3(B_ * SO_), dim3(256), 0, stream, src, x, gn,
                     posid, kept, outs, outx, outpos);
}